// Round 2
// baseline (237.587 us; speedup 1.0000x reference)
//
#include <hip/hip_runtime.h>
#include <hip/hip_bf16.h>

// TensorTrainLMN: out[b, a*128+h] = X[b,:] @ W[:, a*128+h] + bias
//   X[b] = [nh[b,0,:128], ..., nh[b,15,:128], te[b,:128]]   (K = 2176)
//   W folded on-device in f32 from the tiny parameter tensors, stored bf16.
// Kernel 1 (tt_fold): per (aggr, child) block computes A @ B^(15-c) @ U_out
//   via binary exponentiation in LDS (f32, exact vs reference math).
// Kernel 2 (tt_gemm): bf16 MFMA GEMM, M=32768 N=512 K=2176, 128x256 tile,
//   BK=32, double-buffered LDS (80B-padded rows -> even bank spread),
//   reg-staged f32->bf16 RNE conversion, XCD-paired N-tiles for L2 reuse.

typedef short bf16x8 __attribute__((ext_vector_type(8)));
typedef float f32x4  __attribute__((ext_vector_type(4)));

__device__ __forceinline__ unsigned f2bfbits(float f) {
    unsigned u = __builtin_bit_cast(unsigned, f);
    return (u + 0x7FFFu + ((u >> 16) & 1u)) >> 16;   // round-to-nearest-even
}

__device__ __forceinline__ uint2 pack4(float4 v) {
    uint2 r;
    r.x = f2bfbits(v.x) | (f2bfbits(v.y) << 16);
    r.y = f2bfbits(v.z) | (f2bfbits(v.w) << 16);
    return r;
}

// ---------------------------------------------------------------------------
// Fold kernel: build W_bf16[512][2176] and bias[512] from small params.
// Grid: 72 blocks x 256 threads.
//   blocks 0..63  : (a = b>>4, c = b&15)  -> W rows k in [c*128, c*128+128)
//   blocks 64..67 : a = b-64, type path   -> W rows k in [2048, 2176)
//   blocks 68..71 : a = b-68, bias
// ---------------------------------------------------------------------------
__global__ __launch_bounds__(256) void tt_fold(
    const float* __restrict__ Ag,    // (4,128,64)
    const float* __restrict__ Bg,    // (4,64,64)
    const float* __restrict__ Abg,   // (4,1,64)
    const float* __restrict__ Utg,   // (4,128,64)
    const float* __restrict__ btg,   // (4,1,64)
    const float* __restrict__ Uog,   // (4,64,128)
    const float* __restrict__ bog,   // (4,1,128)
    unsigned short* __restrict__ Wb, // [512][2176] bf16 (n-major)
    float* __restrict__ biasOut)     // [512]
{
    __shared__ __align__(16) float L[16384];  // 64 KB, carved below
    const int t = threadIdx.x;
    const int bid = blockIdx.x;

    // d = x @ y (+ add), all 64x64 row-major stride 64 in LDS. No barriers.
    auto mm = [&](float* d, const float* x, const float* y, const float* add) {
        const int r = t >> 2, c0 = (t & 3) << 4;
        float acc[16];
#pragma unroll
        for (int j = 0; j < 16; ++j) acc[j] = 0.f;
        for (int k = 0; k < 64; ++k) {
            const float a = x[r * 64 + k];
            const float4* yr = (const float4*)(y + k * 64 + c0);
#pragma unroll
            for (int jj = 0; jj < 4; ++jj) {
                float4 v = yr[jj];
                acc[4 * jj + 0] += a * v.x;
                acc[4 * jj + 1] += a * v.y;
                acc[4 * jj + 2] += a * v.z;
                acc[4 * jj + 3] += a * v.w;
            }
        }
        if (add) {
#pragma unroll
            for (int j = 0; j < 16; ++j) acc[j] += add[r * 64 + c0 + j];
        }
#pragma unroll
        for (int j = 0; j < 16; ++j) d[r * 64 + c0 + j] = acc[j];
    };

    // element-wise assignment (aggregate init of LDS pointers miscompiles:
    // "unsupported expression in static initializer" on gfx950)
    float* buf[4];
    buf[0] = L;
    buf[1] = L + 4096;
    buf[2] = L + 8192;
    buf[3] = L + 12288;

    if (bid < 68) {
        int a, p, kbase;
        const float* src;
        if (bid < 64) { a = bid >> 4; const int c = bid & 15; p = 15 - c; kbase = c * 128; src = Ag  + a * 8192; }
        else          { a = bid - 64; p = 16; kbase = 2048;               src = Utg + a * 8192; }
        const float* Bmat = Bg + a * 4096;

        // base = B in buf0/1 (pingpong), res = I in buf2/3 (pingpong)
        for (int i = t; i < 4096; i += 256) {
            buf[0][i] = Bmat[i];
            buf[2][i] = ((i >> 6) == (i & 63)) ? 1.f : 0.f;
        }
        __syncthreads();
        int bcur = 0, rcur = 2;
        int e = p;
        while (e) {
            if (e & 1) { mm(buf[rcur ^ 1], buf[rcur], buf[bcur], nullptr); rcur ^= 1; __syncthreads(); }
            e >>= 1;
            if (e)     { mm(buf[bcur ^ 1], buf[bcur], buf[bcur], nullptr); bcur ^= 1; __syncthreads(); }
        }

        // move P = B^p to canonical slot L+8320 (reg-buffered: overlap-safe)
        {
            float tmp[16];
#pragma unroll
            for (int j = 0; j < 16; ++j) tmp[j] = buf[rcur][t * 16 + j];
            __syncthreads();
            float* P = L + 8320;
#pragma unroll
            for (int j = 0; j < 16; ++j) P[t * 16 + j] = tmp[j];
        }
        __syncthreads();

        // M1 = src(128x64) @ P, stored stride-65 at L+0 (bank-conflict-free reads)
        const float* P = L + 8320;
        float* M1 = L;
        {
            const int i = t >> 1, r0 = (t & 1) << 5;
            float acc[32];
#pragma unroll
            for (int j = 0; j < 32; ++j) acc[j] = 0.f;
            for (int q = 0; q < 64; ++q) {
                const float av = src[i * 64 + q];
                const float4* pr = (const float4*)(P + q * 64 + r0);
#pragma unroll
                for (int jj = 0; jj < 8; ++jj) {
                    float4 v = pr[jj];
                    acc[4 * jj + 0] += av * v.x;
                    acc[4 * jj + 1] += av * v.y;
                    acc[4 * jj + 2] += av * v.z;
                    acc[4 * jj + 3] += av * v.w;
                }
            }
#pragma unroll
            for (int j = 0; j < 32; ++j) M1[i * 65 + r0 + j] = acc[j];
        }
        __syncthreads();

        // W2 = M1(128x64) @ Uo(64x128); Uo staged 16 rows/chunk at L+12416
        const float* UoA = Uog + a * 8192;
        float* UC = L + 12416;
        const int i = t >> 1, h0 = (t & 1) << 6;
        float acc2[64];
#pragma unroll
        for (int j = 0; j < 64; ++j) acc2[j] = 0.f;
        for (int ch = 0; ch < 4; ++ch) {
            __syncthreads();
            for (int idx = t; idx < 2048; idx += 256) UC[idx] = UoA[ch * 2048 + idx];
            __syncthreads();
            for (int rr = 0; rr < 16; ++rr) {
                const float m = M1[i * 65 + ch * 16 + rr];
                const float4* ur = (const float4*)(UC + rr * 128 + h0);
#pragma unroll
                for (int jj = 0; jj < 16; ++jj) {
                    float4 v = ur[jj];
                    acc2[4 * jj + 0] += m * v.x;
                    acc2[4 * jj + 1] += m * v.y;
                    acc2[4 * jj + 2] += m * v.z;
                    acc2[4 * jj + 3] += m * v.w;
                }
            }
        }
#pragma unroll
        for (int j = 0; j < 64; ++j)
            Wb[(size_t)(a * 128 + h0 + j) * 2176 + kbase + i] =
                (unsigned short)f2bfbits(acc2[j]);
    } else {
        // bias block: S16 = sum_{p<16} B^p, B16 = B^16 via S_{2n}=S_n+B^n S_n
        const int a = bid - 68;
        const float* Bmat = Bg + a * 4096;
        for (int i = t; i < 4096; i += 256) {
            buf[0][i] = Bmat[i];
            buf[2][i] = ((i >> 6) == (i & 63)) ? 1.f : 0.f;
        }
        __syncthreads();
        int bcur = 0, scur = 2;
        for (int rnd = 0; rnd < 4; ++rnd) {
            mm(buf[scur ^ 1], buf[bcur], buf[scur], buf[scur]); // S' = B^n@S + S
            mm(buf[bcur ^ 1], buf[bcur], buf[bcur], nullptr);   // B^{2n}
            __syncthreads();
            scur ^= 1; bcur ^= 1;
        }
        // scur == 2 (S16), bcur == 0 (B16); buf[1]/buf[3] free
        float* vv = buf[3];
        if (t < 64) {
            float acc = 0.f;
            const float* S16 = buf[scur];
            const float* B16 = buf[bcur];
            for (int q = 0; q < 64; ++q)
                acc += Abg[a * 64 + q] * S16[q * 64 + t]
                     + btg[a * 64 + q] * B16[q * 64 + t];
            vv[t] = acc;
        }
        __syncthreads();
        if (t < 128) {
            float accb = bog[a * 128 + t];
            const float* UoA = Uog + a * 8192;
            for (int r = 0; r < 64; ++r) accb += vv[r] * UoA[r * 128 + t];
            biasOut[a * 128 + t] = accb;
        }
    }
}

// ---------------------------------------------------------------------------
// Main GEMM: out[32768,512] = X[32768,2176](f32->bf16) @ W[2176,512](bf16) + bias
// BM=128 BN=256 BK=32, 512 threads (8 waves, 2x4), per-wave 64x64 (4x4 frags),
// mfma_f32_16x16x32_bf16, double-buffered LDS, 1 barrier per K-step.
// ---------------------------------------------------------------------------
__global__ __launch_bounds__(512) void tt_gemm(
    const float* __restrict__ nh,          // (32768,16,128)
    const float* __restrict__ te,          // (32768,128)
    const unsigned short* __restrict__ Wb, // [512][2176] bf16
    const float* __restrict__ bias,        // [512]
    float* __restrict__ out)               // (32768,512)
{
    __shared__ __align__(16) unsigned short Al[2][128][40]; // 80B rows (pad)
    __shared__ __align__(16) unsigned short Bl[2][256][40];

    const int t = threadIdx.x;
    const int hw = blockIdx.x;
    // XCD pairing: the two N-tiles of one M-panel land on the same XCD,
    // co-resident -> second reader hits L2 for the shared X panel.
    const int lt = (hw & 7) * 64 + (hw >> 3);      // bijective, 512 = 8*64
    const int m0 = (lt >> 1) * 128;
    const int n0 = (lt & 1) * 256;

    const int wave = t >> 6, lane = t & 63;
    const int wr = wave >> 2, wc = wave & 3;       // 2x4 wave grid
    const int lx = lane & 15, lg = lane >> 4;

    const int sar = t >> 3, sac = (t & 7) * 4;     // A staging: 8 thr/row
    const int sbn = t >> 1, sbk = (t & 1) * 16;    // B staging: 2 thr/row

    f32x4 acc[4][4] = {};

    float4 pa0, pa1;
    uint4  pb0, pb1;

    auto loadT = [&](int kt) {
        const int ko = kt * 32;
        if (ko < 2048) {
            const float* p = nh + (size_t)(m0 + sar) * 2048 + ko + sac;
            pa0 = *(const float4*)p;
            pa1 = *(const float4*)(p + (size_t)64 * 2048);
        } else {
            const float* p = te + (size_t)(m0 + sar) * 128 + (ko - 2048) + sac;
            pa0 = *(const float4*)p;
            pa1 = *(const float4*)(p + (size_t)64 * 128);
        }
        const unsigned short* q = Wb + (size_t)(n0 + sbn) * 2176 + ko + sbk;
        pb0 = *(const uint4*)q;
        pb1 = *(const uint4*)(q + 8);
    };
    auto storeT = [&](int b) {
        *(uint2*)&Al[b][sar][sac]      = pack4(pa0);
        *(uint2*)&Al[b][sar + 64][sac] = pack4(pa1);
        *(uint4*)&Bl[b][sbn][sbk]      = pb0;
        *(uint4*)&Bl[b][sbn][sbk + 8]  = pb1;
    };

    loadT(0);
    storeT(0);
    loadT(1);
    __syncthreads();

    for (int kt = 0; kt < 68; ++kt) {
        const int cur = kt & 1;
        bf16x8 aF[4], bF[4];
        const unsigned short* Ab = &Al[cur][wr * 64 + lx][lg * 8];
        const unsigned short* Bb = &Bl[cur][wc * 64 + lx][lg * 8];
#pragma unroll
        for (int f = 0; f < 4; ++f) {
            aF[f] = *(const bf16x8*)(Ab + f * 640);   // +16 rows * 40
            bF[f] = *(const bf16x8*)(Bb + f * 640);
        }
#pragma unroll
        for (int fm = 0; fm < 4; ++fm)
#pragma unroll
            for (int fn = 0; fn < 4; ++fn)
                acc[fm][fn] = __builtin_amdgcn_mfma_f32_16x16x32_bf16(
                    aF[fm], bF[fn], acc[fm][fn], 0, 0, 0);

        if (kt + 1 < 68) {
            storeT(cur ^ 1);          // tile kt+1 (regs loaded last iter)
            if (kt + 2 < 68) loadT(kt + 2);
        }
        __syncthreads();
    }

    // epilogue: C/D layout col = lane&15, row = (lane>>4)*4 + reg  [m89]
    const int ob = m0 + wr * 64 + lg * 4;
    const int oc = n0 + wc * 64 + lx;
    float bv[4];
#pragma unroll
    for (int fn = 0; fn < 4; ++fn) bv[fn] = bias[oc + fn * 16];
#pragma unroll
    for (int fm = 0; fm < 4; ++fm)
#pragma unroll
        for (int fn = 0; fn < 4; ++fn)
#pragma unroll
            for (int j = 0; j < 4; ++j)
                out[(size_t)(ob + fm * 16 + j) * 512 + oc + fn * 16] =
                    acc[fm][fn][j] + bv[fn];
}

// ---------------------------------------------------------------------------
extern "C" void kernel_launch(void* const* d_in, const int* in_sizes, int n_in,
                              void* d_out, int out_size, void* d_ws, size_t ws_size,
                              hipStream_t stream) {
    const float* nh  = (const float*)d_in[0];  // neighbour_h
    const float* te  = (const float*)d_in[1];  // type_embs
    const float* Ag  = (const float*)d_in[2];  // A
    const float* Bg  = (const float*)d_in[3];  // B
    const float* Abg = (const float*)d_in[4];  // A_b
    const float* Utg = (const float*)d_in[5];  // U_type
    const float* btg = (const float*)d_in[6];  // b_type
    const float* Uog = (const float*)d_in[7];  // U_output
    const float* bog = (const float*)d_in[8];  // b_output

    unsigned short* Wb = (unsigned short*)d_ws;              // 512*2176*2 B
    float* bias = (float*)((char*)d_ws + (size_t)512 * 2176 * 2);
    float* out = (float*)d_out;

    hipLaunchKernelGGL(tt_fold, dim3(72), dim3(256), 0, stream,
                       Ag, Bg, Abg, Utg, btg, Uog, bog, Wb, bias);
    hipLaunchKernelGGL(tt_gemm, dim3(512), dim3(512), 0, stream,
                       nh, te, Wb, bias, out);
}